// Round 11
// baseline (643.442 us; speedup 1.0000x reference)
//
#include <hip/hip_runtime.h>
#include <hip/hip_fp16.h>
#include <math.h>

#define N_LEVELS 16
#define LOG2_T 19
#define TABLE_SIZE (1 << LOG2_T)
#define IDX_MASK ((unsigned)(TABLE_SIZE - 1))
#define N_STAGED 2                  // L0..L1 dense in LDS
#define N_LDS 2728                  // 1000 + 1728 entries = 10.9 KB
#define THREADS 256
#define GRID_BLOCKS 2048            // 8 blocks/CU x 256 CU

typedef float f2_t __attribute__((ext_vector_type(2)));
typedef float f4_t __attribute__((ext_vector_type(4)));

struct Params {
    float res[N_LEVELS];
    int   c0[N_STAGED];
    int   K[N_STAGED];
    int   K2[N_STAGED];
    int   base[N_STAGED + 1];
    int   n_pts;
};

// ---- pass 1a: fp16-compress ALL 16 tables into workspace (~25 us).
// Values in [-1e-4,1e-4]; fp16 abs err ~3e-8 (absmax unchanged rounds 1-9).
__global__ __launch_bounds__(256) void convert_all(
    const f2_t* __restrict__ emb, unsigned* __restrict__ tab, int n)
{
    int i = blockIdx.x * 256 + threadIdx.x;
    if (i >= n) return;
    f2_t e = __builtin_nontemporal_load(&emb[i]);
    union { __half2 h2; unsigned u; } c;
    c.h2 = __floats2half2_rn(e.x, e.y);
    __builtin_nontemporal_store(c.u, &tab[i]);
}

// ---- pass 1b: dense re-indexed coarse tables (L0..L1), fp16.
__global__ __launch_bounds__(256) void build_dense(
    const f2_t* __restrict__ emb, unsigned* __restrict__ dense, Params P)
{
    int t = blockIdx.x * 256 + threadIdx.x;
    if (t >= P.base[N_STAGED]) return;
    int lev = (t >= P.base[1]) ? 1 : 0;
    int li = t - P.base[lev];
    int K  = P.K[lev];
    if (li >= K * K * K) return;               // padding slot
    int kx = li % K; int r2 = li / K; int ky = r2 % K; int kz = r2 / K;
    unsigned cx = (unsigned)(P.c0[lev] + kx);
    unsigned cy = (unsigned)(P.c0[lev] + ky);
    unsigned cz = (unsigned)(P.c0[lev] + kz);
    unsigned h = (cx ^ (cy * 2654435761u) ^ (cz * 805459861u)) & IDX_MASK;
    f2_t e = emb[(size_t)lev * TABLE_SIZE + h];
    union { __half2 h2; unsigned u; } c;
    c.h2 = __floats2half2_rn(e.x, e.y);
    dense[t] = c.u;
}

__device__ __forceinline__ void acc_corner(
    unsigned w0, unsigned w1, float g0, float g1, float& a0, float& a1)
{
    union { unsigned u; __half2 h; } p0, p1;
    p0.u = w0; p1.u = w1;
    a0 += g0 * __low2float(p0.h)  + g1 * __low2float(p1.h);
    a1 += g0 * __high2float(p0.h) + g1 * __high2float(p1.h);
}

// EXACT fp32 op sequence of the verified baseline (add, div, floor; no FMA
// contraction of the vmin term).
#define GRID_SETUP(gridv)                                                  \
    float tx = (xx + 1.0f) / (gridv);                                      \
    float ty = (xy + 1.0f) / (gridv);                                      \
    float tz = (xz + 1.0f) / (gridv);                                      \
    int blx = (int)floorf(tx);                                             \
    int bly = (int)floorf(ty);                                             \
    int blz = (int)floorf(tz);                                             \
    float wx = (xx - ((float)blx * (gridv) + -1.0f)) / (gridv);            \
    float wy = (xy - ((float)bly * (gridv) + -1.0f)) / (gridv);            \
    float wz = (xz - ((float)blz * (gridv) + -1.0f)) / (gridv);            \
    float fy[2] = {1.0f - wy, wy};                                         \
    float fz[2] = {1.0f - wz, wz};                                         \
    float fx0 = 1.0f - wx, fx1 = wx;

// Hashed fp16 level — 8B PAIR loads (R3-proven numerics). Width model
// (rounds 0-9): divergent 16B lanes cost ~3.3 cyc (return-bound), 8B lanes
// ~2.1 (addr-rate floor). 6 ops/level at 2.1 beats 5 ops at 3.3.
// x-prime==1: i1 = i0^1 iff blx even -> aligned 8B pair covers both x-corners
// for even-blx lanes; odd lanes patch with one 4B gather (50%).
__device__ __forceinline__ void eval_hash(
    float grid, const unsigned* __restrict__ tab,
    float xx, float xy, float xz, float& a0, float& a1)
{
    GRID_SETUP(grid)
    unsigned ux  = (unsigned)blx;
    unsigned hy0 = (unsigned)bly * 2654435761u;
    unsigned hy1 = ((unsigned)bly + 1u) * 2654435761u;
    unsigned hz0 = (unsigned)blz * 805459861u;
    unsigned hz1 = ((unsigned)blz + 1u) * 805459861u;
    unsigned i0a[4], i1a[4];
#pragma unroll
    for (int yz = 0; yz < 4; ++yz) {
        unsigned hyz = ((yz & 2) ? hy1 : hy0) ^ ((yz & 1) ? hz1 : hz0);
        i0a[yz] = (ux ^ hyz) & IDX_MASK;
        i1a[yz] = ((ux + 1u) ^ hyz) & IDX_MASK;
    }
    uint2 g[4];
#pragma unroll
    for (int yz = 0; yz < 4; ++yz)
        g[yz] = *(const uint2*)(tab + (i0a[yz] & ~1u));    // aligned 8B
    unsigned w0a[4], w1a[4];
#pragma unroll
    for (int yz = 0; yz < 4; ++yz) {
        w0a[yz] = (i0a[yz] & 1u) ? g[yz].y : g[yz].x;
        w1a[yz] = (i0a[yz] & 1u) ? g[yz].x : g[yz].y;      // valid iff ux even
    }
    if (ux & 1u) {                                         // odd lanes: real bx=1
#pragma unroll
        for (int yz = 0; yz < 4; ++yz) w1a[yz] = tab[i1a[yz]];
    }
    a0 = 0.0f; a1 = 0.0f;
#pragma unroll
    for (int yz = 0; yz < 4; ++yz) {
        float wyz = fy[yz >> 1] * fz[yz & 1];
        acc_corner(w0a[yz], w1a[yz], fx0 * wyz, fx1 * wyz, a0, a1);
    }
}

// LDS dense coarse level (R4/R8/R9-proven): x-neighbors adjacent.
template <int LEV>
__device__ __forceinline__ void eval_lds(
    const Params& P, const unsigned* s_dense, const f2_t* __restrict__ emb,
    float xx, float xy, float xz, float& a0, float& a1)
{
    float grid = 2.0f / P.res[LEV];
    GRID_SETUP(grid)
    int K = P.K[LEV], K2 = P.K2[LEV];
    int kx = blx - P.c0[LEV], ky = bly - P.c0[LEV], kz = blz - P.c0[LEV];
    a0 = 0.0f; a1 = 0.0f;
    unsigned lim = (unsigned)(K - 1);
    if ((unsigned)kx < lim && (unsigned)ky < lim && (unsigned)kz < lim) {
        int ib = P.base[LEV] + (kz * K + ky) * K + kx;
#pragma unroll
        for (int yz = 0; yz < 4; ++yz) {
            int id = ib + (yz >> 1) * K + (yz & 1) * K2;
            float wyz = fy[yz >> 1] * fz[yz & 1];
            acc_corner(s_dense[id], s_dense[id + 1], fx0 * wyz, fx1 * wyz,
                       a0, a1);
        }
    } else {
        // cold safety fallback: exact f32 hash gathers (corner outside box)
        const f2_t* tab = emb + (size_t)LEV * TABLE_SIZE;
#pragma unroll
        for (int k = 0; k < 8; ++k) {
            int bx = (k >> 2) & 1, by = (k >> 1) & 1, bz = k & 1;
            unsigned h = ((unsigned)(blx + bx)
                          ^ ((unsigned)(bly + by) * 2654435761u)
                          ^ ((unsigned)(blz + bz) * 805459861u)) & IDX_MASK;
            f2_t e = tab[h];
            float w = (bx ? wx : 1.0f - wx) * fy[by] * fz[bz];
            a0 += w * e.x; a1 += w * e.y;
        }
    }
}

// ---- pass 2: thread = point (grid-stride), all 16 levels serial, uniform
// path, 8B gathers throughout.
__global__ __launch_bounds__(256) void ingp_hash_v10(
    const float* __restrict__ x,
    const unsigned* __restrict__ tabAll,
    const unsigned* __restrict__ denseG,
    const f2_t* __restrict__ emb,
    float* __restrict__ out,
    Params P)
{
    __shared__ __align__(16) unsigned s_dense[N_LDS];
    {
        const uint4* src = (const uint4*)denseG;
        uint4* dst = (uint4*)s_dense;
        for (int id = threadIdx.x; id < N_LDS / 4; id += THREADS)
            dst[id] = src[id];
    }
    __syncthreads();

#pragma unroll 1
    for (int n = blockIdx.x * THREADS + (int)threadIdx.x; n < P.n_pts;
         n += GRID_BLOCKS * THREADS) {

        // one 16B x load (3 used floats; last point falls back to scalars)
        float xx, xy, xz;
        if (n < P.n_pts - 1) {
            f4_t v;
            __builtin_memcpy(&v, x + 3 * (size_t)n, 16);
            xx = v.x; xy = v.y; xz = v.z;
        } else {
            xx = x[3 * (size_t)n]; xy = x[3 * (size_t)n + 1]; xz = x[3 * (size_t)n + 2];
        }
        xx = fminf(fmaxf(xx, -1.0f), 1.0f);
        xy = fminf(fmaxf(xy, -1.0f), 1.0f);
        xz = fminf(fmaxf(xz, -1.0f), 1.0f);

        float* orow = out + (size_t)n * (N_LEVELS * 2);
        float a0, a1, b0, b1;

        // pair 0: L0, L1 from LDS
        eval_lds<0>(P, s_dense, emb, xx, xy, xz, a0, a1);
        eval_lds<1>(P, s_dense, emb, xx, xy, xz, b0, b1);
        { f4_t o = {a0, a1, b0, b1};
          __builtin_nontemporal_store(o, (f4_t*)(orow + 0)); }

        // pairs 1..7: L2..L15 hashed
#pragma unroll
        for (int p = 1; p < 8; ++p) {
            eval_hash(2.0f / P.res[2 * p], tabAll + (size_t)(2 * p) * TABLE_SIZE,
                      xx, xy, xz, a0, a1);
            eval_hash(2.0f / P.res[2 * p + 1], tabAll + (size_t)(2 * p + 1) * TABLE_SIZE,
                      xx, xy, xz, b0, b1);
            f4_t o = {a0, a1, b0, b1};
            __builtin_nontemporal_store(o, (f4_t*)(orow + p * 4));
        }
    }
}

// ---- fallback (ws unavailable): round-3 proven f32 pair kernel.
__global__ __launch_bounds__(256) void ingp_hash_pair_f32(
    const float* __restrict__ x, const f2_t* __restrict__ emb,
    float* __restrict__ out, int n_pts, Params P)
{
    int b = blockIdx.x;
    int slot = b & 7;
    int n = (b >> 3) * 256 + (int)threadIdx.x;
    if (n >= n_pts) return;
    float xx = fminf(fmaxf(x[n * 3 + 0], -1.0f), 1.0f);
    float xy = fminf(fmaxf(x[n * 3 + 1], -1.0f), 1.0f);
    float xz = fminf(fmaxf(x[n * 3 + 2], -1.0f), 1.0f);
    float r0 = 0.f, r1 = 0.f, r2 = 0.f, r3 = 0.f;
#pragma unroll
    for (int hl = 0; hl < 2; ++hl) {
        int lev = 2 * slot + hl;
        float grid = 2.0f / P.res[lev];
        int blx = (int)floorf((xx + 1.0f) / grid);
        int bly = (int)floorf((xy + 1.0f) / grid);
        int blz = (int)floorf((xz + 1.0f) / grid);
        float wx = (xx - ((float)blx * grid + -1.0f)) / grid;
        float wy = (xy - ((float)bly * grid + -1.0f)) / grid;
        float wz = (xz - ((float)blz * grid + -1.0f)) / grid;
        const f2_t* tab = emb + (size_t)lev * TABLE_SIZE;
        float acc0 = 0.0f, acc1 = 0.0f;
#pragma unroll
        for (int k = 0; k < 8; ++k) {
            int bx = (k >> 2) & 1, by = (k >> 1) & 1, bz = k & 1;
            unsigned h = ((unsigned)(blx + bx)
                          ^ ((unsigned)(bly + by) * 2654435761u)
                          ^ ((unsigned)(blz + bz) * 805459861u)) & IDX_MASK;
            f2_t e = tab[h];
            float w = (bx ? wx : 1.0f - wx) * (by ? wy : 1.0f - wy) * (bz ? wz : 1.0f - wz);
            acc0 += w * e.x; acc1 += w * e.y;
        }
        if (hl == 0) { r0 = acc0; r1 = acc1; } else { r2 = acc0; r3 = acc1; }
    }
    f4_t o4 = {r0, r1, r2, r3};
    __builtin_nontemporal_store(o4, (f4_t*)(out + (size_t)n * (N_LEVELS * 2) + slot * 4));
}

extern "C" void kernel_launch(void* const* d_in, const int* in_sizes, int n_in,
                              void* d_out, int out_size, void* d_ws, size_t ws_size,
                              hipStream_t stream) {
    const float* x   = (const float*)d_in[0];
    const float* emb = (const float*)d_in[1];
    float* out = (float*)d_out;
    int n_pts = in_sizes[0] / 3;

    Params P;
    // RESOLUTIONS: numpy float64 semantics on host (same libm as np)
    double b = exp((log(512.0) - log(16.0)) / 15.0);
    for (int i = 0; i < N_LEVELS; ++i)
        P.res[i] = (float)floor(16.0 * pow(b, (double)i));
    P.n_pts = n_pts;

    // Dense box bounds with the SAME fp32 ops the device uses (x in [0,1]).
    int base = 0;
    for (int l = 0; l < N_STAGED; ++l) {
        float grid = 2.0f / P.res[l];
        int blmin = (int)floorf(1.0f / grid);
        int blmax = (int)floorf(2.0f / grid);
        int K = blmax - blmin + 2;
        P.c0[l] = blmin; P.K[l] = K; P.K2[l] = K * K;
        P.base[l] = base;
        base += K * K * K;
        base = (base + 3) & ~3;        // 4-entry align each segment
    }
    P.base[N_STAGED] = base;

    size_t need = (size_t)N_LEVELS * TABLE_SIZE * 4 + (size_t)N_LDS * 4;
    bool ok = (base == N_LDS) && (ws_size >= need) && (d_ws != nullptr);
    if (ok) {
        unsigned* tabAll = (unsigned*)d_ws;
        unsigned* denseG = tabAll + (size_t)N_LEVELS * TABLE_SIZE;
        int nAll = N_LEVELS * TABLE_SIZE;
        hipLaunchKernelGGL(convert_all, dim3((nAll + 255) / 256), dim3(256), 0, stream,
                           (const f2_t*)emb, tabAll, nAll);
        hipLaunchKernelGGL(build_dense, dim3((base + 255) / 256), dim3(256), 0, stream,
                           (const f2_t*)emb, denseG, P);
        hipLaunchKernelGGL(ingp_hash_v10, dim3(GRID_BLOCKS), dim3(256), 0, stream,
                           x, tabAll, denseG, (const f2_t*)emb, out, P);
    } else {
        int blocks = 8 * ((n_pts + 255) / 256);
        hipLaunchKernelGGL(ingp_hash_pair_f32, dim3(blocks), dim3(256), 0, stream,
                           x, (const f2_t*)emb, out, n_pts, P);
    }
}